// Round 2
// baseline (4757.355 us; speedup 1.0000x reference)
//
#include <hip/hip_runtime.h>
#include <hip/hip_bf16.h>

namespace {

constexpr int kB = 512, kN = 32, kHS = 512, kHS2 = 1024, kHS3 = 1536;
constexpr int kGS = 1024, kNZ = 56, kTE = 3;

// ---------------- H init (chunk): H[m,:] = finit_w[nt[m],:] + finit_b -------
__global__ __launch_bounds__(256) void hinit_kernel(const int* __restrict__ nt,
    const float* __restrict__ finit_w, const float* __restrict__ finit_b,
    float* __restrict__ H)
{
    int idx = blockIdx.x * 256 + threadIdx.x;  // < MC*kHS (grid exact)
    int m = idx >> 9;
    int h = idx & 511;
    int t = nt[m];
    H[idx] = finit_w[t * kHS + h] + finit_b[h];
}

// ---------------- deg[b,v] = sum_u adj[b,u,v]  (full batch, once) -----------
__global__ __launch_bounds__(256) void deg_kernel(const float* __restrict__ adj,
    float* __restrict__ deg)
{
    int idx = blockIdx.x * 256 + threadIdx.x;  // < kB*kN
    int b = idx >> 5, v = idx & 31;
    const float* p = adj + (size_t)b * kN * kN + v;
    float s = 0.f;
    #pragma unroll
    for (int u = 0; u < kN; ++u) s += p[u * kN];
    deg[idx] = s;
}

// ---------------- has_pred[v] = (sum_b deg[b,v]) > 0 ------------------------
__global__ void haspred_kernel(const float* __restrict__ deg, int* __restrict__ hp)
{
    int v = threadIdx.x;  // 32 threads
    float s = 0.f;
    for (int b = 0; b < kB; ++b) s += deg[b * kN + v];
    hp[v] = (s > 0.f) ? 1 : 0;
}

// ---------------- biasE[e] = fe_w[HS,e] + fe_b[e]  (once) -------------------
__global__ void biasE_kernel(const float* __restrict__ fe_w,
    const float* __restrict__ fe_b, float* __restrict__ biasE)
{
    int e = blockIdx.x * 256 + threadIdx.x;  // < kHS2
    biasE[e] = fe_w[(size_t)kHS * kHS2 + e] + fe_b[e];
}

// ---------------- biasRZ[t,e] = bih[t,e] + bhh[t,e], e<1024  (once) ---------
__global__ void biasRZ_kernel(const float* __restrict__ bih,
    const float* __restrict__ bhh, float* __restrict__ biasRZ)
{
    int idx = blockIdx.x * 256 + threadIdx.x;  // < kTE*kHS2
    int t = idx >> 10, e = idx & 1023;
    biasRZ[idx] = bih[t * kHS3 + e] + bhh[t * kHS3 + e];
}

// ---------------- tiled fp32 GEMM: C = [C +] A @ B (+bias) ------------------
// A: (M,K) row-major.  BT=false: B (K,N) row-major.  BT=true: B (N,K).
// Tile 128x128, BK=16, 256 threads, 8x8 per thread.
template<bool BT, bool ACC>
__global__ __launch_bounds__(256, 2) void gemm_f32(const float* __restrict__ A,
    const float* __restrict__ Bm, float* __restrict__ C,
    const float* __restrict__ bias, int M_, int N_, int K_)
{
    __shared__ float As[16][132];
    __shared__ float Bs[16][132];
    const int tid = threadIdx.x;
    const int mT = blockIdx.y * 128;
    const int nT = blockIdx.x * 128;
    const int tx = tid & 15;
    const int ty = tid >> 4;

    float acc[8][8];
    #pragma unroll
    for (int i = 0; i < 8; ++i)
        #pragma unroll
        for (int j = 0; j < 8; ++j) acc[i][j] = 0.f;

    for (int kt = 0; kt < K_; kt += 16) {
        #pragma unroll
        for (int l = 0; l < 2; ++l) {
            int f = tid + l * 256;
            int row = f >> 2;
            int kq  = f & 3;
            const float4 v = *reinterpret_cast<const float4*>(
                A + (size_t)(mT + row) * K_ + kt + kq * 4);
            As[kq * 4 + 0][row] = v.x;
            As[kq * 4 + 1][row] = v.y;
            As[kq * 4 + 2][row] = v.z;
            As[kq * 4 + 3][row] = v.w;
        }
        #pragma unroll
        for (int l = 0; l < 2; ++l) {
            int f = tid + l * 256;
            if (!BT) {
                int k  = f >> 5;
                int j4 = f & 31;
                const float4 v = *reinterpret_cast<const float4*>(
                    Bm + (size_t)(kt + k) * N_ + nT + j4 * 4);
                *reinterpret_cast<float4*>(&Bs[k][j4 * 4]) = v;
            } else {
                int col = f >> 2;
                int kq  = f & 3;
                const float4 v = *reinterpret_cast<const float4*>(
                    Bm + (size_t)(nT + col) * K_ + kt + kq * 4);
                Bs[kq * 4 + 0][col] = v.x;
                Bs[kq * 4 + 1][col] = v.y;
                Bs[kq * 4 + 2][col] = v.z;
                Bs[kq * 4 + 3][col] = v.w;
            }
        }
        __syncthreads();
        #pragma unroll
        for (int k = 0; k < 16; ++k) {
            float4 a0 = *reinterpret_cast<const float4*>(&As[k][ty * 8]);
            float4 a1 = *reinterpret_cast<const float4*>(&As[k][ty * 8 + 4]);
            float4 b0 = *reinterpret_cast<const float4*>(&Bs[k][tx * 4]);
            float4 b1 = *reinterpret_cast<const float4*>(&Bs[k][64 + tx * 4]);
            float a[8] = {a0.x, a0.y, a0.z, a0.w, a1.x, a1.y, a1.z, a1.w};
            float b[8] = {b0.x, b0.y, b0.z, b0.w, b1.x, b1.y, b1.z, b1.w};
            #pragma unroll
            for (int i = 0; i < 8; ++i)
                #pragma unroll
                for (int j = 0; j < 8; ++j)
                    acc[i][j] = fmaf(a[i], b[j], acc[i][j]);
        }
        __syncthreads();
    }

    float bj[8];
    #pragma unroll
    for (int j = 0; j < 4; ++j) {
        bj[j]     = bias ? bias[nT + tx * 4 + j]      : 0.f;
        bj[4 + j] = bias ? bias[nT + 64 + tx * 4 + j] : 0.f;
    }
    #pragma unroll
    for (int i = 0; i < 8; ++i) {
        size_t rowOff = (size_t)(mT + ty * 8 + i) * N_;
        float4 v0 = {acc[i][0] + bj[0], acc[i][1] + bj[1],
                     acc[i][2] + bj[2], acc[i][3] + bj[3]};
        float4 v1 = {acc[i][4] + bj[4], acc[i][5] + bj[5],
                     acc[i][6] + bj[6], acc[i][7] + bj[7]};
        if (ACC) {
            float4 o0 = *reinterpret_cast<const float4*>(C + rowOff + nT + tx * 4);
            float4 o1 = *reinterpret_cast<const float4*>(C + rowOff + nT + 64 + tx * 4);
            v0.x += o0.x; v0.y += o0.y; v0.z += o0.z; v0.w += o0.w;
            v1.x += o1.x; v1.y += o1.y; v1.z += o1.z; v1.w += o1.w;
        }
        *reinterpret_cast<float4*>(C + rowOff + nT + tx * 4)      = v0;
        *reinterpret_cast<float4*>(C + rowOff + nT + 64 + tx * 4) = v1;
    }
}

template<bool BT, bool ACC>
void launch_gemm(const float* A, const float* Bm, float* C, const float* bias,
                 int M_, int N_, int K_, hipStream_t stream)
{
    dim3 grid(N_ / 128, M_ / 128);
    gemm_f32<BT, ACC><<<grid, 256, 0, stream>>>(A, Bm, C, bias, M_, N_, K_);
}

// ---------------- Av[b,v,e] = sum_u adj[b,u,v]*Hu[b,u,e] + deg[b,v]*St[b,v,e]
// In-place into St. blockIdx.y = local graph index within chunk.
__global__ __launch_bounds__(256) void av_kernel(const float* __restrict__ adj,
    const float* __restrict__ Hu, const float* __restrict__ deg,
    float* __restrict__ StAv)
{
    __shared__ float adjs[kN * kN];
    __shared__ float degs[kN];
    int b = blockIdx.y;
    int e = blockIdx.x * 256 + threadIdx.x;
    {
        const float4* src = reinterpret_cast<const float4*>(adj + (size_t)b * kN * kN);
        float4 v = src[threadIdx.x];
        *reinterpret_cast<float4*>(&adjs[threadIdx.x * 4]) = v;
        if (threadIdx.x < kN) degs[threadIdx.x] = deg[b * kN + threadIdx.x];
    }
    __syncthreads();

    const size_t base = (size_t)b * kN * kHS2 + e;
    float acc[kN];
    #pragma unroll
    for (int v = 0; v < kN; ++v) acc[v] = degs[v] * StAv[base + (size_t)v * kHS2];
    for (int u = 0; u < kN; ++u) {
        float hu = Hu[base + (size_t)u * kHS2];
        #pragma unroll
        for (int v4 = 0; v4 < kN / 4; ++v4) {
            float4 a = *reinterpret_cast<const float4*>(&adjs[u * kN + v4 * 4]);
            acc[v4 * 4 + 0] = fmaf(a.x, hu, acc[v4 * 4 + 0]);
            acc[v4 * 4 + 1] = fmaf(a.y, hu, acc[v4 * 4 + 1]);
            acc[v4 * 4 + 2] = fmaf(a.z, hu, acc[v4 * 4 + 2]);
            acc[v4 * 4 + 3] = fmaf(a.w, hu, acc[v4 * 4 + 3]);
        }
    }
    #pragma unroll
    for (int v = 0; v < kN; ++v) StAv[base + (size_t)v * kHS2] = acc[v];
}

// ---------------- GRU gating + has_pred select (H in place) -----------------
// gxz: (MC,1024) cols [0,512)=xr+hr, [512,1024)=xz+hz (biases included)
// xn : (MC,512) = Av@wih_n^T + bih_n ; hn: (MC,512) = H@whh_n^T + bhh_n
__global__ __launch_bounds__(256) void gru_kernel(float* __restrict__ H,
    const float* __restrict__ gxz, const float* __restrict__ xn,
    const float* __restrict__ hn, const int* __restrict__ hp)
{
    int idx = blockIdx.x * 256 + threadIdx.x;  // < MC*kHS
    int m = idx >> 9;
    int h = idx & 511;
    float rp = gxz[(size_t)m * kHS2 + h];
    float zp = gxz[(size_t)m * kHS2 + kHS + h];
    float r = 1.f / (1.f + __expf(-rp));
    float z = 1.f / (1.f + __expf(-zp));
    float n = tanhf(xn[idx] + r * hn[idx]);
    float hold = H[idx];
    float hnew = (1.f - z) * n + z * hold;
    H[idx] = hp[m & 31] ? hnew : hold;
}

// ---------------- Hg[b,g] = sum_n sigmoid(G1[b,n,g]) * G2[b,n,g] ------------
__global__ __launch_bounds__(256) void hg_kernel(const float* __restrict__ G1,
    const float* __restrict__ G2, float* __restrict__ Hg)
{
    int idx = blockIdx.x * 256 + threadIdx.x;  // < CH*kGS
    int b = idx >> 10, g = idx & 1023;
    size_t base = (size_t)b * kN * kGS + g;
    float acc = 0.f;
    #pragma unroll 8
    for (int n = 0; n < kN; ++n) {
        float s = G1[base + (size_t)n * kGS];
        float sig = 1.f / (1.f + __expf(-s));
        acc = fmaf(sig, G2[base + (size_t)n * kGS], acc);
    }
    Hg[idx] = acc;
}

// ---------------- mu/logvar heads (per chunk; bglob = b0 + blockIdx.x) ------
__global__ __launch_bounds__(64) void fc_kernel(const float* __restrict__ Hg,
    const float* __restrict__ fc1_w, const float* __restrict__ fc1_b,
    const float* __restrict__ fc2_w, const float* __restrict__ fc2_b,
    float* __restrict__ out, int b0)
{
    __shared__ float hg[kGS];
    int bl = blockIdx.x;
    for (int i = threadIdx.x; i < kGS; i += 64) hg[i] = Hg[(size_t)bl * kGS + i];
    __syncthreads();
    int j = threadIdx.x;
    if (j < kNZ) {
        float s1 = fc1_b[j], s2 = fc2_b[j];
        for (int k = 0; k < kGS; ++k) {
            float h = hg[k];
            s1 = fmaf(h, fc1_w[k * kNZ + j], s1);
            s2 = fmaf(h, fc2_w[k * kNZ + j], s2);
        }
        int bg = b0 + bl;
        out[(size_t)bg * kNZ + j] = s1;
        out[(size_t)kB * kNZ + (size_t)bg * kNZ + j] = s2;
    }
}

}  // namespace

extern "C" void kernel_launch(void* const* d_in, const int* in_sizes, int n_in,
                              void* d_out, int out_size, void* d_ws, size_t ws_size,
                              hipStream_t stream)
{
    const int*   node_types = (const int*)  d_in[0];
    const float* adj        = (const float*)d_in[1];
    const float* finit_w    = (const float*)d_in[2];
    const float* finit_b    = (const float*)d_in[3];
    const float* fe_w       = (const float*)d_in[4];
    const float* fe_b       = (const float*)d_in[5];
    const float* grue_wih   = (const float*)d_in[6];
    const float* grue_whh   = (const float*)d_in[7];
    const float* grue_bih   = (const float*)d_in[8];
    const float* grue_bhh   = (const float*)d_in[9];
    const float* gate_w     = (const float*)d_in[10];
    const float* gate_b     = (const float*)d_in[11];
    const float* mapper_w   = (const float*)d_in[12];
    const float* fc1_w      = (const float*)d_in[13];
    const float* fc1_b      = (const float*)d_in[14];
    const float* fc2_w      = (const float*)d_in[15];
    const float* fc2_b      = (const float*)d_in[16];
    float* out = (float*)d_out;

    // ---- fixed small buffers ----
    float* W = (float*)d_ws;
    size_t o = 0;
    float* deg    = W + o; o += (size_t)kB * kN;       // 16384
    int*   hp     = (int*)(W + o); o += 64;
    float* biasE  = W + o; o += kHS2;                  // 1024
    float* biasRZ = W + o; o += kTE * kHS2;            // 3072
    float* Hg     = W + o; o += (size_t)kB * kGS;      // 524288 (max chunk)
    const size_t fixedFloats = o;

    // ---- pick chunk size CH (graphs) to fit ws_size ----
    // per-graph floats: H 32*512 + A 32*1024 + B 32*1024 + C 32*512 = 98304
    const size_t perGraph = 98304;
    int CH = 512;
    while (CH > 4 &&
           (fixedFloats + (size_t)CH * perGraph) * sizeof(float) > ws_size)
        CH >>= 1;

    // ---- global precompute ----
    deg_kernel<<<kB * kN / 256, 256, 0, stream>>>(adj, deg);
    haspred_kernel<<<1, kN, 0, stream>>>(deg, hp);
    biasE_kernel<<<kHS2 / 256, 256, 0, stream>>>(fe_w, fe_b, biasE);
    biasRZ_kernel<<<kTE * kHS2 / 256, 256, 0, stream>>>(grue_bih, grue_bhh, biasRZ);

    const float* Wn = fe_w;
    const float* Ws = fe_w + (size_t)(kHS + 1) * kHS2;

    for (int b0 = 0; b0 < kB; b0 += CH) {
        const int MC = CH * kN;  // rows in chunk (multiple of 128)
        float* Hc = W + fixedFloats;
        float* Ab = Hc + (size_t)MC * kHS;    // MC x 1024: Hu -> gxz -> G1
        float* Bb = Ab + (size_t)MC * kHS2;   // MC x 1024: St/Av -> hn -> G2
        float* Cb = Bb + (size_t)MC * kHS2;   // MC x 512 : xn

        hinit_kernel<<<MC * kHS / 256, 256, 0, stream>>>(
            node_types + (size_t)b0 * kN, finit_w, finit_b, Hc);

        for (int t = 0; t < kTE; ++t) {
            const float* wih = grue_wih + (size_t)t * kHS3 * kHS2;
            const float* whh = grue_whh + (size_t)t * kHS3 * kHS;
            // Hu = H @ Wn
            launch_gemm<false, false>(Hc, Wn, Ab, nullptr, MC, kHS2, kHS, stream);
            // St = H @ Ws + biasE
            launch_gemm<false, false>(Hc, Ws, Bb, biasE, MC, kHS2, kHS, stream);
            // Av in place into Bb
            {
                dim3 g(kHS2 / 256, CH);
                av_kernel<<<g, 256, 0, stream>>>(
                    adj + (size_t)b0 * kN * kN, Ab, deg + (size_t)b0 * kN, Bb);
            }
            // gxz = Av @ wih_rz^T + (bih+bhh)_rz   (into Ab; Hu dead)
            launch_gemm<true, false>(Bb, wih, Ab, biasRZ + t * kHS2,
                                     MC, kHS2, kHS2, stream);
            // gxz += H @ whh_rz^T
            launch_gemm<true, true>(Hc, whh, Ab, nullptr, MC, kHS2, kHS, stream);
            // xn = Av @ wih_n^T + bih_n            (into Cb)
            launch_gemm<true, false>(Bb, wih + (size_t)kHS2 * kHS2, Cb,
                                     grue_bih + t * kHS3 + kHS2, MC, kHS, kHS2, stream);
            // hn = H @ whh_n^T + bhh_n             (into Bb; Av dead)
            launch_gemm<true, false>(Hc, whh + (size_t)kHS2 * kHS, Bb,
                                     grue_bhh + t * kHS3 + kHS2, MC, kHS, kHS, stream);
            // GRU gating
            gru_kernel<<<MC * kHS / 256, 256, 0, stream>>>(Hc, Ab, Cb, Bb, hp);
        }

        // readout: G1 = H@gate_w + gate_b (Ab), G2 = H@mapper_w (Bb)
        launch_gemm<false, false>(Hc, gate_w, Ab, gate_b, MC, kGS, kHS, stream);
        launch_gemm<false, false>(Hc, mapper_w, Bb, nullptr, MC, kGS, kHS, stream);
        hg_kernel<<<CH * kGS / 256, 256, 0, stream>>>(Ab, Bb, Hg);
        fc_kernel<<<CH, 64, 0, stream>>>(Hg, fc1_w, fc1_b, fc2_w, fc2_b, out, b0);
    }
}

// Round 3
// 1194.557 us; speedup vs baseline: 3.9825x; 3.9825x over previous
//
#include <hip/hip_runtime.h>
#include <hip/hip_bf16.h>

namespace {

constexpr int kB = 512, kN = 32, kHS = 512, kHS2 = 1024, kHS3 = 1536;
constexpr int kGS = 1024, kNZ = 56, kTE = 3;

typedef __attribute__((ext_vector_type(8))) short bf16x8;
typedef __attribute__((ext_vector_type(4))) float f32x4;

__device__ inline ushort f2bf(float f) {
    union { float f; unsigned u; } v; v.f = f;
    unsigned r = v.u + 0x7fffu + ((v.u >> 16) & 1u);
    return (ushort)(r >> 16);
}
__device__ inline float bf2f(ushort b) {
    union { unsigned u; float f; } v; v.u = ((unsigned)b) << 16;
    return v.f;
}

// ---------------- one-time weight prep --------------------------------------
// out[n*512+k] = bf16(in[k*N + n])   (transpose KxN -> N-major, K=512)
__global__ __launch_bounds__(256) void convT512_kernel(const float* __restrict__ in,
    ushort* __restrict__ out, int N)
{
    int idx = blockIdx.x * 256 + threadIdx.x;  // < N*512
    int n = idx >> 9, k = idx & 511;
    out[idx] = f2bf(in[(size_t)k * N + n]);
}

// catRZ[t][n][k] = k<1024 ? wih[t][n][k] : whh[t][n][k-1024]   (n<1024)
__global__ __launch_bounds__(256) void catrz_kernel(const float* __restrict__ wih,
    const float* __restrict__ whh, ushort* __restrict__ out)
{
    int k = blockIdx.x * 256 + threadIdx.x;  // <1536
    int n = blockIdx.y, t = blockIdx.z;
    float v = (k < kHS2) ? wih[((size_t)t * kHS3 + n) * kHS2 + k]
                         : whh[((size_t)t * kHS3 + n) * kHS + (k - kHS2)];
    out[((size_t)t * kHS2 + n) * kHS3 + k] = f2bf(v);
}

// wihN[t][n][k] = wih[t][1024+n][k]  (n<512, k<1024)
__global__ __launch_bounds__(256) void wihn_kernel(const float* __restrict__ wih,
    ushort* __restrict__ out)
{
    int k = blockIdx.x * 256 + threadIdx.x;
    int n = blockIdx.y, t = blockIdx.z;
    out[((size_t)t * kHS + n) * kHS2 + k] =
        f2bf(wih[((size_t)t * kHS3 + kHS2 + n) * kHS2 + k]);
}

// whhN[t][n][k] = whh[t][1024+n][k]  (n<512, k<512)
__global__ __launch_bounds__(256) void whhn_kernel(const float* __restrict__ whh,
    ushort* __restrict__ out)
{
    int k = blockIdx.x * 256 + threadIdx.x;
    int n = blockIdx.y, t = blockIdx.z;
    out[((size_t)t * kHS + n) * kHS + k] =
        f2bf(whh[((size_t)t * kHS3 + kHS2 + n) * kHS + k]);
}

// ---------------- small precompute ------------------------------------------
__global__ __launch_bounds__(256) void deg_kernel(const float* __restrict__ adj,
    float* __restrict__ deg)
{
    int idx = blockIdx.x * 256 + threadIdx.x;  // < kB*kN
    int b = idx >> 5, v = idx & 31;
    const float* p = adj + (size_t)b * kN * kN + v;
    float s = 0.f;
    #pragma unroll
    for (int u = 0; u < kN; ++u) s += p[u * kN];
    deg[idx] = s;
}

__global__ void haspred_kernel(const float* __restrict__ deg, int* __restrict__ hp)
{
    int v = threadIdx.x;  // 32
    float s = 0.f;
    for (int b = 0; b < kB; ++b) s += deg[b * kN + v];
    hp[v] = (s > 0.f) ? 1 : 0;
}

__global__ void biasE_kernel(const float* __restrict__ fe_w,
    const float* __restrict__ fe_b, float* __restrict__ biasE)
{
    int e = blockIdx.x * 256 + threadIdx.x;  // < kHS2
    biasE[e] = fe_w[(size_t)kHS * kHS2 + e] + fe_b[e];
}

__global__ void biasRZ_kernel(const float* __restrict__ bih,
    const float* __restrict__ bhh, float* __restrict__ biasRZ)
{
    int idx = blockIdx.x * 256 + threadIdx.x;  // < kTE*kHS2
    int t = idx >> 10, e = idx & 1023;
    biasRZ[idx] = bih[t * kHS3 + e] + bhh[t * kHS3 + e];
}

// ---------------- H init: AvH[m, 1024+h] = bf16(finit_w[nt[m],h]+finit_b[h]) -
__global__ __launch_bounds__(256) void hinit_kernel(const int* __restrict__ nt,
    const float* __restrict__ finit_w, const float* __restrict__ finit_b,
    ushort* __restrict__ AvH)
{
    int idx = blockIdx.x * 256 + threadIdx.x;  // < MC*kHS
    int m = idx >> 9;
    int h = idx & 511;
    int t = nt[m];
    AvH[(size_t)m * kHS3 + kHS2 + h] = f2bf(finit_w[t * kHS + h] + finit_b[h]);
}

// ---------------- MFMA bf16 GEMM: C(f32) = A(bf16) @ B(bf16)^T (+bias) ------
// A: (M,K) bf16 with row stride lda. B: (N,K) bf16 dense. C: (M,N) f32 dense.
// 128x128 tile, BK=32, 256 threads (4 waves, 2x2), 4x4 16x16x32 frags/wave.
__global__ __launch_bounds__(256) void gemm_bf16(const ushort* __restrict__ A,
    const ushort* __restrict__ B, float* __restrict__ C,
    const float* __restrict__ bias, int M_, int N_, int K_, int lda)
{
    __shared__ ushort As[128 * 32];
    __shared__ ushort Bs[128 * 32];
    const int tid = threadIdx.x;
    const int w = tid >> 6, l = tid & 63;
    const int mT = blockIdx.y * 128, nT = blockIdx.x * 128;
    const int wm = w >> 1, wn = w & 1;

    f32x4 acc[4][4] = {};

    const int lrow  = l >> 2;        // 0..15
    const int lkoff = (l & 3) * 8;   // 0,8,16,24

    for (int kt = 0; kt < K_; kt += 32) {
        #pragma unroll
        for (int i = 0; i < 2; ++i) {
            int c = w * 2 + i;  // 0..7, 16 rows each
            const ushort* ga = A + (size_t)(mT + c * 16 + lrow) * lda + kt + lkoff;
            __builtin_amdgcn_global_load_lds(
                (const __attribute__((address_space(1))) void*)ga,
                (__attribute__((address_space(3))) void*)(As + c * 512),
                16, 0, 0);
            const ushort* gb = B + (size_t)(nT + c * 16 + lrow) * K_ + kt + lkoff;
            __builtin_amdgcn_global_load_lds(
                (const __attribute__((address_space(1))) void*)gb,
                (__attribute__((address_space(3))) void*)(Bs + c * 512),
                16, 0, 0);
        }
        __syncthreads();

        bf16x8 af[4], bfr[4];
        #pragma unroll
        for (int mi = 0; mi < 4; ++mi)
            af[mi] = *reinterpret_cast<const bf16x8*>(
                &As[(wm * 64 + mi * 16 + (l & 15)) * 32 + (l >> 4) * 8]);
        #pragma unroll
        for (int ni = 0; ni < 4; ++ni)
            bfr[ni] = *reinterpret_cast<const bf16x8*>(
                &Bs[(wn * 64 + ni * 16 + (l & 15)) * 32 + (l >> 4) * 8]);
        #pragma unroll
        for (int mi = 0; mi < 4; ++mi)
            #pragma unroll
            for (int ni = 0; ni < 4; ++ni)
                acc[mi][ni] = __builtin_amdgcn_mfma_f32_16x16x32_bf16(
                    af[mi], bfr[ni], acc[mi][ni], 0, 0, 0);
        __syncthreads();
    }

    // epilogue: C/D layout col=lane&15, row=(lane>>4)*4+q
    const int col0 = l & 15;
    const int row0 = (l >> 4) * 4;
    #pragma unroll
    for (int ni = 0; ni < 4; ++ni) {
        int col = nT + wn * 64 + ni * 16 + col0;
        float bv = bias ? bias[col] : 0.f;
        #pragma unroll
        for (int mi = 0; mi < 4; ++mi) {
            #pragma unroll
            for (int q = 0; q < 4; ++q) {
                int row = mT + wm * 64 + mi * 16 + row0 + q;
                C[(size_t)row * N_ + col] = acc[mi][ni][q] + bv;
            }
        }
    }
}

void launch_gemm(const ushort* A, int lda, const ushort* B, float* C,
                 const float* bias, int M_, int N_, int K_, hipStream_t stream)
{
    dim3 grid(N_ / 128, M_ / 128);
    gemm_bf16<<<grid, 256, 0, stream>>>(A, B, C, bias, M_, N_, K_, lda);
}

// ---- Av[b,v,e] = sum_u adj[b,u,v]*Hu[b,u,e] + deg[b,v]*St[b,v,e] -> bf16 ---
__global__ __launch_bounds__(256) void av_kernel(const float* __restrict__ adj,
    const float* __restrict__ Hu, const float* __restrict__ deg,
    const float* __restrict__ St, ushort* __restrict__ AvH)
{
    __shared__ float adjs[kN * kN];
    __shared__ float degs[kN];
    int b = blockIdx.y;
    int e = blockIdx.x * 256 + threadIdx.x;
    {
        const float4* src = reinterpret_cast<const float4*>(adj + (size_t)b * kN * kN);
        float4 v = src[threadIdx.x];
        *reinterpret_cast<float4*>(&adjs[threadIdx.x * 4]) = v;
        if (threadIdx.x < kN) degs[threadIdx.x] = deg[b * kN + threadIdx.x];
    }
    __syncthreads();

    const size_t base = (size_t)b * kN * kHS2 + e;
    float acc[kN];
    #pragma unroll
    for (int v = 0; v < kN; ++v) acc[v] = degs[v] * St[base + (size_t)v * kHS2];
    for (int u = 0; u < kN; ++u) {
        float hu = Hu[base + (size_t)u * kHS2];
        #pragma unroll
        for (int v4 = 0; v4 < kN / 4; ++v4) {
            float4 a = *reinterpret_cast<const float4*>(&adjs[u * kN + v4 * 4]);
            acc[v4 * 4 + 0] = fmaf(a.x, hu, acc[v4 * 4 + 0]);
            acc[v4 * 4 + 1] = fmaf(a.y, hu, acc[v4 * 4 + 1]);
            acc[v4 * 4 + 2] = fmaf(a.z, hu, acc[v4 * 4 + 2]);
            acc[v4 * 4 + 3] = fmaf(a.w, hu, acc[v4 * 4 + 3]);
        }
    }
    const size_t obase = (size_t)b * kN * kHS3 + e;
    #pragma unroll
    for (int v = 0; v < kN; ++v) AvH[obase + (size_t)v * kHS3] = f2bf(acc[v]);
}

// ---------------- GRU gating + has_pred select (H bf16 inside AvH) ----------
__global__ __launch_bounds__(256) void gru_kernel(ushort* __restrict__ AvH,
    const float* __restrict__ gxz, const float* __restrict__ xn,
    const float* __restrict__ hn, const int* __restrict__ hp)
{
    int idx = blockIdx.x * 256 + threadIdx.x;  // < MC*kHS
    int m = idx >> 9;
    int h = idx & 511;
    float rp = gxz[(size_t)m * kHS2 + h];
    float zp = gxz[(size_t)m * kHS2 + kHS + h];
    float r = 1.f / (1.f + __expf(-rp));
    float z = 1.f / (1.f + __expf(-zp));
    float n = tanhf(xn[idx] + r * hn[idx]);
    ushort* Hp = AvH + (size_t)m * kHS3 + kHS2 + h;
    float hold = bf2f(*Hp);
    float hnew = (1.f - z) * n + z * hold;
    *Hp = hp[m & 31] ? f2bf(hnew) : f2bf(hold);
}

// ---------------- Hg[b,g] = sum_n sigmoid(G1[b,n,g]) * G2[b,n,g] ------------
__global__ __launch_bounds__(256) void hg_kernel(const float* __restrict__ G1,
    const float* __restrict__ G2, float* __restrict__ Hg)
{
    int idx = blockIdx.x * 256 + threadIdx.x;  // < CH*kGS
    int b = idx >> 10, g = idx & 1023;
    size_t base = (size_t)b * kN * kGS + g;
    float acc = 0.f;
    #pragma unroll 8
    for (int n = 0; n < kN; ++n) {
        float s = G1[base + (size_t)n * kGS];
        float sig = 1.f / (1.f + __expf(-s));
        acc = fmaf(sig, G2[base + (size_t)n * kGS], acc);
    }
    Hg[idx] = acc;
}

// ---------------- mu/logvar heads -------------------------------------------
__global__ __launch_bounds__(64) void fc_kernel(const float* __restrict__ Hg,
    const float* __restrict__ fc1_w, const float* __restrict__ fc1_b,
    const float* __restrict__ fc2_w, const float* __restrict__ fc2_b,
    float* __restrict__ out, int b0)
{
    __shared__ float hg[kGS];
    int bl = blockIdx.x;
    for (int i = threadIdx.x; i < kGS; i += 64) hg[i] = Hg[(size_t)bl * kGS + i];
    __syncthreads();
    int j = threadIdx.x;
    if (j < kNZ) {
        float s1 = fc1_b[j], s2 = fc2_b[j];
        for (int k = 0; k < kGS; ++k) {
            float h = hg[k];
            s1 = fmaf(h, fc1_w[k * kNZ + j], s1);
            s2 = fmaf(h, fc2_w[k * kNZ + j], s2);
        }
        int bg = b0 + bl;
        out[(size_t)bg * kNZ + j] = s1;
        out[(size_t)kB * kNZ + (size_t)bg * kNZ + j] = s2;
    }
}

}  // namespace

extern "C" void kernel_launch(void* const* d_in, const int* in_sizes, int n_in,
                              void* d_out, int out_size, void* d_ws, size_t ws_size,
                              hipStream_t stream)
{
    const int*   node_types = (const int*)  d_in[0];
    const float* adj        = (const float*)d_in[1];
    const float* finit_w    = (const float*)d_in[2];
    const float* finit_b    = (const float*)d_in[3];
    const float* fe_w       = (const float*)d_in[4];
    const float* fe_b       = (const float*)d_in[5];
    const float* grue_wih   = (const float*)d_in[6];
    const float* grue_whh   = (const float*)d_in[7];
    const float* grue_bih   = (const float*)d_in[8];
    const float* grue_bhh   = (const float*)d_in[9];
    const float* gate_w     = (const float*)d_in[10];
    const float* gate_b     = (const float*)d_in[11];
    const float* mapper_w   = (const float*)d_in[12];
    const float* fc1_w      = (const float*)d_in[13];
    const float* fc1_b      = (const float*)d_in[14];
    const float* fc2_w      = (const float*)d_in[15];
    const float* fc2_b      = (const float*)d_in[16];
    float* out = (float*)d_out;

    // ---- fixed region (float units; every block multiple of 4 floats) ----
    float* W = (float*)d_ws;
    size_t o = 0;
    float*  deg    = W + o; o += (size_t)kB * kN;              // 16384
    int*    hp     = (int*)(W + o); o += 64;
    float*  biasE  = W + o; o += kHS2;
    float*  biasRZ = W + o; o += kTE * kHS2;
    float*  Hg     = W + o; o += (size_t)kB * kGS;             // 524288
    ushort* WnT    = (ushort*)(W + o); o += (size_t)kHS2 * kHS / 2;       // 1024x512 bf16
    ushort* WsT    = (ushort*)(W + o); o += (size_t)kHS2 * kHS / 2;
    ushort* catRZ  = (ushort*)(W + o); o += (size_t)kTE * kHS2 * kHS3 / 2; // 3x1024x1536
    ushort* wihN   = (ushort*)(W + o); o += (size_t)kTE * kHS * kHS2 / 2;  // 3x512x1024
    ushort* whhN   = (ushort*)(W + o); o += (size_t)kTE * kHS * kHS / 2;   // 3x512x512
    ushort* gateT  = (ushort*)(W + o); o += (size_t)kGS * kHS / 2;
    ushort* mapT   = (ushort*)(W + o); o += (size_t)kGS * kHS / 2;
    const size_t fixedFloats = o;

    // per-graph floats: AvH bf16 32x1536 (=24576 fl) + Ab 32x1024 + Bb 32x1024
    //                   + Cb 32x512 = 106496
    const size_t perGraph = 106496;
    int CH = 512;
    while (CH > 4 &&
           (fixedFloats + (size_t)CH * perGraph) * sizeof(float) > ws_size)
        CH >>= 1;

    // ---- one-time precompute ----
    deg_kernel<<<kB * kN / 256, 256, 0, stream>>>(adj, deg);
    haspred_kernel<<<1, kN, 0, stream>>>(deg, hp);
    biasE_kernel<<<kHS2 / 256, 256, 0, stream>>>(fe_w, fe_b, biasE);
    biasRZ_kernel<<<kTE * kHS2 / 256, 256, 0, stream>>>(grue_bih, grue_bhh, biasRZ);
    convT512_kernel<<<kHS2 * kHS / 256, 256, 0, stream>>>(fe_w, WnT, kHS2);
    convT512_kernel<<<kHS2 * kHS / 256, 256, 0, stream>>>(
        fe_w + (size_t)(kHS + 1) * kHS2, WsT, kHS2);
    catrz_kernel<<<dim3(kHS3 / 256, kHS2, kTE), 256, 0, stream>>>(grue_wih, grue_whh, catRZ);
    wihn_kernel<<<dim3(kHS2 / 256, kHS, kTE), 256, 0, stream>>>(grue_wih, wihN);
    whhn_kernel<<<dim3(kHS / 256, kHS, kTE), 256, 0, stream>>>(grue_whh, whhN);
    convT512_kernel<<<kGS * kHS / 256, 256, 0, stream>>>(gate_w, gateT, kGS);
    convT512_kernel<<<kGS * kHS / 256, 256, 0, stream>>>(mapper_w, mapT, kGS);

    for (int b0 = 0; b0 < kB; b0 += CH) {
        const int MC = CH * kN;  // rows (multiple of 128)
        ushort* AvH = (ushort*)(W + fixedFloats);            // MC x 1536 bf16
        float*  Ab  = W + fixedFloats + (size_t)MC * 768;    // MC x 1024 f32
        float*  Bb  = Ab + (size_t)MC * kHS2;                // MC x 1024 f32
        float*  Cb  = Bb + (size_t)MC * kHS2;                // MC x 512  f32
        ushort* Hc  = AvH + kHS2;                            // H view, lda 1536

        hinit_kernel<<<MC * kHS / 256, 256, 0, stream>>>(
            node_types + (size_t)b0 * kN, finit_w, finit_b, AvH);

        for (int t = 0; t < kTE; ++t) {
            // Hu = H @ WnT^T            -> Ab (MC x 1024)
            launch_gemm(Hc, kHS3, WnT, Ab, nullptr, MC, kHS2, kHS, stream);
            // St = H @ WsT^T + biasE    -> Bb
            launch_gemm(Hc, kHS3, WsT, Bb, biasE, MC, kHS2, kHS, stream);
            // Av -> AvH[:, 0:1024] (bf16)
            {
                dim3 g(kHS2 / 256, CH);
                av_kernel<<<g, 256, 0, stream>>>(
                    adj + (size_t)b0 * kN * kN, Ab, deg + (size_t)b0 * kN, Bb, AvH);
            }
            // gxz = [Av|H] @ catRZ^T + (bih+bhh)_rz  -> Ab  (K=1536!)
            launch_gemm(AvH, kHS3, catRZ + (size_t)t * kHS2 * kHS3, Ab,
                        biasRZ + t * kHS2, MC, kHS2, kHS3, stream);
            // xn = Av @ wihN^T + bih_n  -> Cb (MC x 512)
            launch_gemm(AvH, kHS3, wihN + (size_t)t * kHS * kHS2, Cb,
                        grue_bih + t * kHS3 + kHS2, MC, kHS, kHS2, stream);
            // hn = H @ whhN^T + bhh_n   -> Bb (dense MC x 512)
            launch_gemm(Hc, kHS3, whhN + (size_t)t * kHS * kHS, Bb,
                        grue_bhh + t * kHS3 + kHS2, MC, kHS, kHS, stream);
            // GRU gating (H in place, bf16)
            gru_kernel<<<MC * kHS / 256, 256, 0, stream>>>(AvH, Ab, Cb, Bb, hp);
        }

        // readout
        launch_gemm(Hc, kHS3, gateT, Ab, gate_b, MC, kGS, kHS, stream);
        launch_gemm(Hc, kHS3, mapT, Bb, nullptr, MC, kGS, kHS, stream);
        hg_kernel<<<CH * kGS / 256, 256, 0, stream>>>(Ab, Bb, Hg);
        fc_kernel<<<CH, 64, 0, stream>>>(Hg, fc1_w, fc1_b, fc2_w, fc2_b, out, b0);
    }
}

// Round 4
// 922.960 us; speedup vs baseline: 5.1545x; 1.2943x over previous
//
#include <hip/hip_runtime.h>
#include <hip/hip_bf16.h>

namespace {

constexpr int kB = 512, kN = 32, kHS = 512, kHS2 = 1024, kHS3 = 1536;
constexpr int kGS = 1024, kNZ = 56, kTE = 3;

typedef __attribute__((ext_vector_type(8))) short bf16x8;
typedef __attribute__((ext_vector_type(4))) float f32x4;

__device__ inline ushort f2bf(float f) {
    union { float f; unsigned u; } v; v.f = f;
    unsigned r = v.u + 0x7fffu + ((v.u >> 16) & 1u);
    return (ushort)(r >> 16);
}
__device__ inline float bf2f(ushort b) {
    union { unsigned u; float f; } v; v.u = ((unsigned)b) << 16;
    return v.f;
}

// ================= one-time weight prep =====================================
// WnsT (2048 x 512): rows 0-1023 = Wn^T, rows 1024-2047 = Ws^T
__global__ __launch_bounds__(256) void wnst_kernel(const float* __restrict__ fe_w,
    ushort* __restrict__ out)
{
    int idx = blockIdx.x * 256 + threadIdx.x;  // < 2048*512
    int n = idx >> 9, k = idx & 511;
    float v = (n < kHS2) ? fe_w[(size_t)k * kHS2 + n]
                         : fe_w[(size_t)(kHS + 1 + k) * kHS2 + (n - kHS2)];
    out[idx] = f2bf(v);
}

// gateMapT (2048 x 512): rows 0-1023 = gate_w^T, 1024-2047 = mapper_w^T
__global__ __launch_bounds__(256) void gatemap_kernel(const float* __restrict__ gw,
    const float* __restrict__ mw, ushort* __restrict__ out)
{
    int idx = blockIdx.x * 256 + threadIdx.x;  // < 2048*512
    int n = idx >> 9, k = idx & 511;
    float v = (n < kGS) ? gw[(size_t)k * kGS + n] : mw[(size_t)k * kGS + (n - kGS)];
    out[idx] = f2bf(v);
}

// catRZN[t] (1536 x 1536): row n, col k:
//  k<1024: wih[t][n][k];  k>=1024: n<1024 ? whh[t][n][k-1024] : 0
__global__ __launch_bounds__(256) void catrzn_kernel(const float* __restrict__ wih,
    const float* __restrict__ whh, ushort* __restrict__ out)
{
    int k = blockIdx.x * 256 + threadIdx.x;  // <1536
    int n = blockIdx.y, t = blockIdx.z;
    float v;
    if (k < kHS2)       v = wih[((size_t)t * kHS3 + n) * kHS2 + k];
    else if (n < kHS2)  v = whh[((size_t)t * kHS3 + n) * kHS + (k - kHS2)];
    else                v = 0.f;
    out[((size_t)t * kHS3 + n) * kHS3 + k] = f2bf(v);
}

// whhN[t] (512 x 512) = whh[t][1024+n][k]
__global__ __launch_bounds__(256) void whhn_kernel(const float* __restrict__ whh,
    ushort* __restrict__ out)
{
    int k = blockIdx.x * 256 + threadIdx.x;
    int n = blockIdx.y, t = blockIdx.z;
    out[((size_t)t * kHS + n) * kHS + k] =
        f2bf(whh[((size_t)t * kHS3 + kHS2 + n) * kHS + k]);
}

// ================= small precompute =========================================
__global__ __launch_bounds__(256) void deg_kernel(const float* __restrict__ adj,
    float* __restrict__ deg)
{
    int idx = blockIdx.x * 256 + threadIdx.x;  // < kB*kN
    int b = idx >> 5, v = idx & 31;
    const float* p = adj + (size_t)b * kN * kN + v;
    float s = 0.f;
    #pragma unroll
    for (int u = 0; u < kN; ++u) s += p[u * kN];
    deg[idx] = s;
}

__global__ void haspred_kernel(const float* __restrict__ deg, int* __restrict__ hp)
{
    int v = threadIdx.x;  // 32
    float s = 0.f;
    for (int b = 0; b < kB; ++b) s += deg[b * kN + v];
    hp[v] = (s > 0.f) ? 1 : 0;
}

// biasHS (2048): [0 | we+fe_b]
__global__ void biasHS_kernel(const float* __restrict__ fe_w,
    const float* __restrict__ fe_b, float* __restrict__ o)
{
    int e = blockIdx.x * 256 + threadIdx.x;  // < 2048
    o[e] = (e < kHS2) ? 0.f
                      : fe_w[(size_t)kHS * kHS2 + (e - kHS2)] + fe_b[e - kHS2];
}

// biasGXN (t,1536): [bih_rz+bhh_rz | bih_n]
__global__ void biasGXN_kernel(const float* __restrict__ bih,
    const float* __restrict__ bhh, float* __restrict__ o)
{
    int idx = blockIdx.x * 256 + threadIdx.x;  // < kTE*1536
    int t = idx / kHS3, e = idx % kHS3;
    float v = bih[t * kHS3 + e];
    if (e < kHS2) v += bhh[t * kHS3 + e];
    o[idx] = v;
}

// biasRO (2048): [gate_b | 0]
__global__ void biasRO_kernel(const float* __restrict__ gb, float* __restrict__ o)
{
    int e = blockIdx.x * 256 + threadIdx.x;
    o[e] = (e < kGS) ? gb[e] : 0.f;
}

// ---------------- H init: AvH[m, 1024+h] = bf16(finit_w[nt[m],h]+finit_b[h]) -
__global__ __launch_bounds__(256) void hinit_kernel(const int* __restrict__ nt,
    const float* __restrict__ finit_w, const float* __restrict__ finit_b,
    ushort* __restrict__ AvH)
{
    int idx = blockIdx.x * 256 + threadIdx.x;  // < MC*kHS
    int m = idx >> 9;
    int h = idx & 511;
    int t = nt[m];
    AvH[(size_t)m * kHS3 + kHS2 + h] = f2bf(finit_w[t * kHS + h] + finit_b[h]);
}

// ================= MFMA bf16 GEMM: C = A(bf16) @ B(bf16)^T (+bias) ==========
// A: (M,K) bf16, row stride lda. B: (N,K) bf16 dense. C: (M,N) CT dense.
// 128x128 tile, BK=64, 256 thr (4 waves 2x2), 16x16x32 frags, XOR-swizzled LDS
// via pre-swizzled global source (LDS stays linear for global_load_lds).
template<typename CT>
__global__ __launch_bounds__(256) void gemm_bf16(const ushort* __restrict__ A,
    const ushort* __restrict__ B, CT* __restrict__ C,
    const float* __restrict__ bias, int M_, int N_, int K_, int lda)
{
    __shared__ ushort As[128 * 64];   // [row][slot*8] ; content slot = s ^ (row&7)
    __shared__ ushort Bs[128 * 64];
    const int tid = threadIdx.x;
    const int w = tid >> 6, l = tid & 63;
    const int mT = blockIdx.y * 128, nT = blockIdx.x * 128;
    const int wm = w >> 1, wn = w & 1;

    f32x4 acc[4][4] = {};

    const int lr = l >> 3;             // row-within-8-row chunk
    const int ls = (l & 7) ^ lr;       // pre-swizzled global 16B k-slot

    for (int kt = 0; kt < K_; kt += 64) {
        #pragma unroll
        for (int i = 0; i < 4; ++i) {
            int c = w * 4 + i;         // 0..15, 8 rows each
            int row = c * 8 + lr;
            const ushort* ga = A + (size_t)(mT + row) * lda + kt + ls * 8;
            __builtin_amdgcn_global_load_lds(
                (const __attribute__((address_space(1))) void*)ga,
                (__attribute__((address_space(3))) void*)(As + c * 512), 16, 0, 0);
            const ushort* gb = B + (size_t)(nT + row) * K_ + kt + ls * 8;
            __builtin_amdgcn_global_load_lds(
                (const __attribute__((address_space(1))) void*)gb,
                (__attribute__((address_space(3))) void*)(Bs + c * 512), 16, 0, 0);
        }
        __syncthreads();

        #pragma unroll
        for (int kk = 0; kk < 2; ++kk) {
            // lane needs global slot g; LDS slot = g ^ (row&7), row&7 == l&7
            const int s = (kk * 4 + (l >> 4)) ^ (l & 7);
            bf16x8 af[4], bfr[4];
            #pragma unroll
            for (int mi = 0; mi < 4; ++mi) {
                int r = wm * 64 + mi * 16 + (l & 15);
                af[mi] = *reinterpret_cast<const bf16x8*>(&As[r * 64 + s * 8]);
            }
            #pragma unroll
            for (int ni = 0; ni < 4; ++ni) {
                int r = wn * 64 + ni * 16 + (l & 15);
                bfr[ni] = *reinterpret_cast<const bf16x8*>(&Bs[r * 64 + s * 8]);
            }
            #pragma unroll
            for (int mi = 0; mi < 4; ++mi)
                #pragma unroll
                for (int ni = 0; ni < 4; ++ni)
                    acc[mi][ni] = __builtin_amdgcn_mfma_f32_16x16x32_bf16(
                        af[mi], bfr[ni], acc[mi][ni], 0, 0, 0);
        }
        __syncthreads();
    }

    // epilogue: C/D layout col=lane&15, row=(lane>>4)*4+q
    const int col0 = l & 15;
    const int row0 = (l >> 4) * 4;
    #pragma unroll
    for (int ni = 0; ni < 4; ++ni) {
        int col = nT + wn * 64 + ni * 16 + col0;
        float bv = bias ? bias[col] : 0.f;
        #pragma unroll
        for (int mi = 0; mi < 4; ++mi) {
            #pragma unroll
            for (int q = 0; q < 4; ++q) {
                int row = mT + wm * 64 + mi * 16 + row0 + q;
                float val = acc[mi][ni][q] + bv;
                if constexpr (sizeof(CT) == 2)
                    C[(size_t)row * N_ + col] = (CT)f2bf(val);
                else
                    C[(size_t)row * N_ + col] = (CT)val;
            }
        }
    }
}

template<typename CT>
void launch_gemm(const ushort* A, int lda, const ushort* B, CT* C,
                 const float* bias, int M_, int N_, int K_, hipStream_t stream)
{
    dim3 grid(N_ / 128, M_ / 128);
    gemm_bf16<CT><<<grid, 256, 0, stream>>>(A, B, C, bias, M_, N_, K_, lda);
}

// ---- Av[b,v,e] = sum_u adj[b,u,v]*Hu[b,u,e] + deg[b,v]*St[b,v,e] -----------
// HuSt bf16 (M,2048): Hu = cols 0-1023, St = cols 1024-2047. Out: AvH bf16.
__global__ __launch_bounds__(256) void av_kernel(const float* __restrict__ adj,
    const ushort* __restrict__ HuSt, const float* __restrict__ deg,
    ushort* __restrict__ AvH)
{
    __shared__ float adjs[kN * kN];
    __shared__ float degs[kN];
    int b = blockIdx.y;
    int e = blockIdx.x * 256 + threadIdx.x;  // < 1024
    {
        const float4* src = reinterpret_cast<const float4*>(adj + (size_t)b * kN * kN);
        float4 v = src[threadIdx.x];
        *reinterpret_cast<float4*>(&adjs[threadIdx.x * 4]) = v;
        if (threadIdx.x < kN) degs[threadIdx.x] = deg[b * kN + threadIdx.x];
    }
    __syncthreads();

    const size_t rbase = (size_t)b * kN * 2048 + e;
    float acc[kN];
    #pragma unroll
    for (int v = 0; v < kN; ++v)
        acc[v] = degs[v] * bf2f(HuSt[rbase + (size_t)v * 2048 + kHS2]);
    for (int u = 0; u < kN; ++u) {
        float hu = bf2f(HuSt[rbase + (size_t)u * 2048]);
        #pragma unroll
        for (int v4 = 0; v4 < kN / 4; ++v4) {
            float4 a = *reinterpret_cast<const float4*>(&adjs[u * kN + v4 * 4]);
            acc[v4 * 4 + 0] = fmaf(a.x, hu, acc[v4 * 4 + 0]);
            acc[v4 * 4 + 1] = fmaf(a.y, hu, acc[v4 * 4 + 1]);
            acc[v4 * 4 + 2] = fmaf(a.z, hu, acc[v4 * 4 + 2]);
            acc[v4 * 4 + 3] = fmaf(a.w, hu, acc[v4 * 4 + 3]);
        }
    }
    const size_t obase = (size_t)b * kN * kHS3 + e;
    #pragma unroll
    for (int v = 0; v < kN; ++v) AvH[obase + (size_t)v * kHS3] = f2bf(acc[v]);
}

// ---------------- GRU gating + has_pred select (H bf16 inside AvH) ----------
// gxzn bf16 (M,1536): r=cols[0,512), z=[512,1024), xn=[1024,1536). hn bf16 (M,512).
__global__ __launch_bounds__(256) void gru_kernel(ushort* __restrict__ AvH,
    const ushort* __restrict__ gxzn, const ushort* __restrict__ hn,
    const int* __restrict__ hp)
{
    int idx = blockIdx.x * 256 + threadIdx.x;  // < MC*kHS
    int m = idx >> 9;
    int h = idx & 511;
    size_t gb = (size_t)m * kHS3 + h;
    float rp = bf2f(gxzn[gb]);
    float zp = bf2f(gxzn[gb + kHS]);
    float xn = bf2f(gxzn[gb + 2 * kHS]);
    float hv = bf2f(hn[(size_t)m * kHS + h]);
    float r = 1.f / (1.f + __expf(-rp));
    float z = 1.f / (1.f + __expf(-zp));
    float n = tanhf(xn + r * hv);
    ushort* Hp = AvH + (size_t)m * kHS3 + kHS2 + h;
    float hold = bf2f(*Hp);
    float hnew = (1.f - z) * n + z * hold;
    *Hp = hp[m & 31] ? f2bf(hnew) : f2bf(hold);
}

// ---------------- Hg[b,g] = sum_n sigmoid(G1) * G2 --------------------------
// G12 f32 (M,2048): G1 = cols 0-1023 (incl gate_b), G2 = cols 1024-2047
__global__ __launch_bounds__(256) void hg_kernel(const float* __restrict__ G12,
    float* __restrict__ Hg)
{
    int idx = blockIdx.x * 256 + threadIdx.x;  // < CH*kGS
    int b = idx >> 10, g = idx & 1023;
    size_t base = (size_t)b * kN * 2048 + g;
    float acc = 0.f;
    #pragma unroll 8
    for (int n = 0; n < kN; ++n) {
        float s  = G12[base + (size_t)n * 2048];
        float m2 = G12[base + (size_t)n * 2048 + kGS];
        float sig = 1.f / (1.f + __expf(-s));
        acc = fmaf(sig, m2, acc);
    }
    Hg[idx] = acc;
}

// ---------------- mu/logvar heads -------------------------------------------
__global__ __launch_bounds__(64) void fc_kernel(const float* __restrict__ Hg,
    const float* __restrict__ fc1_w, const float* __restrict__ fc1_b,
    const float* __restrict__ fc2_w, const float* __restrict__ fc2_b,
    float* __restrict__ out, int b0)
{
    __shared__ float hg[kGS];
    int bl = blockIdx.x;
    for (int i = threadIdx.x; i < kGS; i += 64) hg[i] = Hg[(size_t)bl * kGS + i];
    __syncthreads();
    int j = threadIdx.x;
    if (j < kNZ) {
        float s1 = fc1_b[j], s2 = fc2_b[j];
        for (int k = 0; k < kGS; ++k) {
            float h = hg[k];
            s1 = fmaf(h, fc1_w[k * kNZ + j], s1);
            s2 = fmaf(h, fc2_w[k * kNZ + j], s2);
        }
        int bg = b0 + bl;
        out[(size_t)bg * kNZ + j] = s1;
        out[(size_t)kB * kNZ + (size_t)bg * kNZ + j] = s2;
    }
}

}  // namespace

extern "C" void kernel_launch(void* const* d_in, const int* in_sizes, int n_in,
                              void* d_out, int out_size, void* d_ws, size_t ws_size,
                              hipStream_t stream)
{
    const int*   node_types = (const int*)  d_in[0];
    const float* adj        = (const float*)d_in[1];
    const float* finit_w    = (const float*)d_in[2];
    const float* finit_b    = (const float*)d_in[3];
    const float* fe_w       = (const float*)d_in[4];
    const float* fe_b       = (const float*)d_in[5];
    const float* grue_wih   = (const float*)d_in[6];
    const float* grue_whh   = (const float*)d_in[7];
    const float* grue_bih   = (const float*)d_in[8];
    const float* grue_bhh   = (const float*)d_in[9];
    const float* gate_w     = (const float*)d_in[10];
    const float* gate_b     = (const float*)d_in[11];
    const float* mapper_w   = (const float*)d_in[12];
    const float* fc1_w      = (const float*)d_in[13];
    const float* fc1_b      = (const float*)d_in[14];
    const float* fc2_w      = (const float*)d_in[15];
    const float* fc2_b      = (const float*)d_in[16];
    float* out = (float*)d_out;

    // ---- fixed region (float units) ----
    float* W = (float*)d_ws;
    size_t o = 0;
    float*  deg     = W + o; o += (size_t)kB * kN;
    int*    hp      = (int*)(W + o); o += 64;
    float*  biasHS  = W + o; o += 2048;
    float*  biasGXN = W + o; o += kTE * kHS3;
    float*  biasRO  = W + o; o += 2048;
    float*  Hg      = W + o; o += (size_t)kB * kGS;
    ushort* WnsT    = (ushort*)(W + o); o += (size_t)2048 * kHS / 2;
    ushort* catRZN  = (ushort*)(W + o); o += (size_t)kTE * kHS3 * kHS3 / 2;
    ushort* whhN    = (ushort*)(W + o); o += (size_t)kTE * kHS * kHS / 2;
    ushort* gateMapT= (ushort*)(W + o); o += (size_t)2048 * kHS / 2;
    const size_t fixedFloats = o;

    // per-graph floats: AvH 24576 + HuSt 32768 + gxzn 24576 + hn 8192 = 90112
    const size_t perGraph = 90112;
    int CH = 512;
    while (CH > 4 &&
           (fixedFloats + (size_t)CH * perGraph) * sizeof(float) > ws_size)
        CH >>= 1;

    // ---- one-time precompute ----
    deg_kernel<<<kB * kN / 256, 256, 0, stream>>>(adj, deg);
    haspred_kernel<<<1, kN, 0, stream>>>(deg, hp);
    biasHS_kernel<<<2048 / 256, 256, 0, stream>>>(fe_w, fe_b, biasHS);
    biasGXN_kernel<<<kTE * kHS3 / 256, 256, 0, stream>>>(grue_bih, grue_bhh, biasGXN);
    biasRO_kernel<<<2048 / 256, 256, 0, stream>>>(gate_b, biasRO);
    wnst_kernel<<<2048 * kHS / 256, 256, 0, stream>>>(fe_w, WnsT);
    catrzn_kernel<<<dim3(kHS3 / 256, kHS3, kTE), 256, 0, stream>>>(grue_wih, grue_whh, catRZN);
    whhn_kernel<<<dim3(kHS / 256, kHS, kTE), 256, 0, stream>>>(grue_whh, whhN);
    gatemap_kernel<<<2048 * kHS / 256, 256, 0, stream>>>(gate_w, mapper_w, gateMapT);

    for (int b0 = 0; b0 < kB; b0 += CH) {
        const int MC = CH * kN;  // rows (multiple of 128)
        ushort* AvH  = (ushort*)(W + fixedFloats);        // MC x 1536 bf16
        ushort* HuSt = AvH  + (size_t)MC * kHS3;          // MC x 2048 bf16
        ushort* gxzn = HuSt + (size_t)MC * 2048;          // MC x 1536 bf16
        ushort* hnb  = gxzn + (size_t)MC * kHS3;          // MC x 512  bf16
        float*  G12  = (float*)HuSt;                      // MC x 2048 f32 (overlay)
        ushort* Hc   = AvH + kHS2;                        // H view, lda 1536

        hinit_kernel<<<MC * kHS / 256, 256, 0, stream>>>(
            node_types + (size_t)b0 * kN, finit_w, finit_b, AvH);

        for (int t = 0; t < kTE; ++t) {
            // HuSt = H @ WnsT^T + [0 | we+fe_b]   (MC x 2048, bf16)
            launch_gemm<ushort>(Hc, kHS3, WnsT, HuSt, biasHS, MC, 2048, kHS, stream);
            // Av -> AvH[:, 0:1024]
            {
                dim3 g(kHS2 / 256, CH);
                av_kernel<<<g, 256, 0, stream>>>(
                    adj + (size_t)b0 * kN * kN, HuSt, deg + (size_t)b0 * kN, AvH);
            }
            // gxzn = [Av|H] @ catRZN[t]^T + biasGXN[t]   (MC x 1536, K=1536)
            launch_gemm<ushort>(AvH, kHS3, catRZN + (size_t)t * kHS3 * kHS3, gxzn,
                                biasGXN + t * kHS3, MC, kHS3, kHS3, stream);
            // hn = H @ whhN[t]^T + bhh_n   (MC x 512)
            launch_gemm<ushort>(Hc, kHS3, whhN + (size_t)t * kHS * kHS, hnb,
                                grue_bhh + t * kHS3 + kHS2, MC, kHS, kHS, stream);
            // GRU gating (H in place)
            gru_kernel<<<MC * kHS / 256, 256, 0, stream>>>(AvH, gxzn, hnb, hp);
        }

        // readout: G12 = H @ [gate|mapper]^T + [gate_b|0]  (MC x 2048, f32)
        launch_gemm<float>(Hc, kHS3, gateMapT, G12, biasRO, MC, 2048, kHS, stream);
        hg_kernel<<<CH * kGS / 256, 256, 0, stream>>>(G12, Hg);
        fc_kernel<<<CH, 64, 0, stream>>>(Hg, fc1_w, fc1_b, fc2_w, fc2_b, out, b0);
    }
}

// Round 7
// 869.958 us; speedup vs baseline: 5.4685x; 1.0609x over previous
//
#include <hip/hip_runtime.h>
#include <hip/hip_bf16.h>

namespace {

constexpr int kB = 512, kN = 32, kHS = 512, kHS2 = 1024, kHS3 = 1536;
constexpr int kGS = 1024, kNZ = 56, kTE = 3;

typedef __attribute__((ext_vector_type(8))) short bf16x8;
typedef __attribute__((ext_vector_type(4))) float f32x4;

__device__ inline ushort f2bf(float f) {
    union { float f; unsigned u; } v; v.f = f;
    unsigned r = v.u + 0x7fffu + ((v.u >> 16) & 1u);
    return (ushort)(r >> 16);
}
__device__ inline float bf2f(ushort b) {
    union { unsigned u; float f; } v; v.u = ((unsigned)b) << 16;
    return v.f;
}

// ================= one-time weight prep =====================================
// WnsT (2048 x 512): rows 0-1023 = Wn^T, rows 1024-2047 = Ws^T
__global__ __launch_bounds__(256) void wnst_kernel(const float* __restrict__ fe_w,
    ushort* __restrict__ out)
{
    int idx = blockIdx.x * 256 + threadIdx.x;  // < 2048*512
    int n = idx >> 9, k = idx & 511;
    float v = (n < kHS2) ? fe_w[(size_t)k * kHS2 + n]
                         : fe_w[(size_t)(kHS + 1 + k) * kHS2 + (n - kHS2)];
    out[idx] = f2bf(v);
}

// gateMapT (2048 x 512): rows 0-1023 = gate_w^T, 1024-2047 = mapper_w^T
__global__ __launch_bounds__(256) void gatemap_kernel(const float* __restrict__ gw,
    const float* __restrict__ mw, ushort* __restrict__ out)
{
    int idx = blockIdx.x * 256 + threadIdx.x;  // < 2048*512
    int n = idx >> 9, k = idx & 511;
    float v = (n < kGS) ? gw[(size_t)k * kGS + n] : mw[(size_t)k * kGS + (n - kGS)];
    out[idx] = f2bf(v);
}

// catRZN[t] (1536 x 1536): row n, col k:
//  k<1024: wih[t][n][k];  k>=1024: n<1024 ? whh[t][n][k-1024] : 0
__global__ __launch_bounds__(256) void catrzn_kernel(const float* __restrict__ wih,
    const float* __restrict__ whh, ushort* __restrict__ out)
{
    int k = blockIdx.x * 256 + threadIdx.x;  // <1536
    int n = blockIdx.y, t = blockIdx.z;
    float v;
    if (k < kHS2)       v = wih[((size_t)t * kHS3 + n) * kHS2 + k];
    else if (n < kHS2)  v = whh[((size_t)t * kHS3 + n) * kHS + (k - kHS2)];
    else                v = 0.f;
    out[((size_t)t * kHS3 + n) * kHS3 + k] = f2bf(v);
}

// whhN[t] (512 x 512) = whh[t][1024+n][k]
__global__ __launch_bounds__(256) void whhn_kernel(const float* __restrict__ whh,
    ushort* __restrict__ out)
{
    int k = blockIdx.x * 256 + threadIdx.x;
    int n = blockIdx.y, t = blockIdx.z;
    out[((size_t)t * kHS + n) * kHS + k] =
        f2bf(whh[((size_t)t * kHS3 + kHS2 + n) * kHS + k]);
}

// ================= small precompute =========================================
__global__ __launch_bounds__(256) void deg_kernel(const float* __restrict__ adj,
    float* __restrict__ deg)
{
    int idx = blockIdx.x * 256 + threadIdx.x;  // < kB*kN
    int b = idx >> 5, v = idx & 31;
    const float* p = adj + (size_t)b * kN * kN + v;
    float s = 0.f;
    #pragma unroll
    for (int u = 0; u < kN; ++u) s += p[u * kN];
    deg[idx] = s;
}

__global__ void haspred_kernel(const float* __restrict__ deg, int* __restrict__ hp)
{
    int v = threadIdx.x;  // 32
    float s = 0.f;
    for (int b = 0; b < kB; ++b) s += deg[b * kN + v];
    hp[v] = (s > 0.f) ? 1 : 0;
}

// biasHS (2048): [0 | we+fe_b]
__global__ void biasHS_kernel(const float* __restrict__ fe_w,
    const float* __restrict__ fe_b, float* __restrict__ o)
{
    int e = blockIdx.x * 256 + threadIdx.x;  // < 2048
    o[e] = (e < kHS2) ? 0.f
                      : fe_w[(size_t)kHS * kHS2 + (e - kHS2)] + fe_b[e - kHS2];
}

// biasGXN (t,1536): [bih_rz+bhh_rz | bih_n]
__global__ void biasGXN_kernel(const float* __restrict__ bih,
    const float* __restrict__ bhh, float* __restrict__ o)
{
    int idx = blockIdx.x * 256 + threadIdx.x;  // < kTE*1536
    int t = idx / kHS3, e = idx % kHS3;
    float v = bih[t * kHS3 + e];
    if (e < kHS2) v += bhh[t * kHS3 + e];
    o[idx] = v;
}

// biasRO (2048): [gate_b | 0]
__global__ void biasRO_kernel(const float* __restrict__ gb, float* __restrict__ o)
{
    int e = blockIdx.x * 256 + threadIdx.x;
    o[e] = (e < kGS) ? gb[e] : 0.f;
}

// ---------------- H init: AvH[m, 1024+h] = bf16(finit_w[nt[m],h]+finit_b[h]) -
__global__ __launch_bounds__(256) void hinit_kernel(const int* __restrict__ nt,
    const float* __restrict__ finit_w, const float* __restrict__ finit_b,
    ushort* __restrict__ AvH)
{
    int idx = blockIdx.x * 256 + threadIdx.x;  // < MC*kHS
    int m = idx >> 9;
    int h = idx & 511;
    int t = nt[m];
    AvH[(size_t)m * kHS3 + kHS2 + h] = f2bf(finit_w[t * kHS + h] + finit_b[h]);
}

// ================= MFMA bf16 GEMM: C = A(bf16) @ B(bf16)^T (+bias) ==========
// A: (M,K) bf16, row stride lda. B: (N,K) bf16 dense. C: (M,N) CT dense.
// BM=128, BN=256, BK=32, 256 thr (4 waves 1Mx4N), wave-tile 128x64 (8x4 frags).
// 3-buffer LDS (72 KB), counted-vmcnt deep pipeline: tile t computes buf[t%3],
// tiles t+1 (landed-by-entry) and t+2 (issuing) in flight; entry wait =
// vmcnt(6) + raw s_barrier. 2 phases/tile, 16 MFMA each, setprio around MFMA.
// LDS rows 64B, 4x16B slots; slot swizzle s' = s ^ ((row>>1)&3), pre-swizzled
// on global source (both-sides rule).
template<typename CT>
__global__ __launch_bounds__(256, 2) void gemm_bf16(const ushort* __restrict__ A,
    const ushort* __restrict__ B, CT* __restrict__ C,
    const float* __restrict__ bias, int M_, int N_, int K_, int lda)
{
    __shared__ ushort smem[3 * 12288];   // per buf: A 128x32 (4096) + B 256x32 (8192)
    const int tid = threadIdx.x;
    const int w = tid >> 6, l = tid & 63;
    const int l15 = l & 15;

    // XCD-aware bijective swizzle (only when nwg % 8 == 0)
    int nwg = gridDim.x * gridDim.y;
    int bid = blockIdx.y * gridDim.x + blockIdx.x;
    int swz = (nwg & 7) ? bid : ((bid & 7) * (nwg >> 3) + (bid >> 3));
    const int bx = swz % gridDim.x, by = swz / gridDim.x;
    const int mT = by * 128, nT = bx * 256;

    const int NT = K_ >> 5;  // BK=32 tiles; NT >= 16 for all our shapes

    auto stage = [&](const ushort* G, int ldg, int rowOff, int buf, int aOff,
                     int idx, int kt2) {
        int row = idx >> 2, sl = idx & 3;
        int gs = sl ^ ((row >> 1) & 3);
        const ushort* g = G + (size_t)(rowOff + row) * ldg + kt2 + gs * 8;
        __builtin_amdgcn_global_load_lds(
            (const __attribute__((address_space(1))) void*)g,
            (__attribute__((address_space(3))) void*)(smem + buf * 12288 + aOff + idx * 8),
            16, 0, 0);
    };
    // stage halves: ph0 = A(2 loads)+B(1), ph1 = B(3)
    auto stage_ph0 = [&](int t) {
        int buf = t % 3, kt2 = t * 32;
        stage(A, lda, mT, buf, 0, tid, kt2);
        stage(A, lda, mT, buf, 0, 256 + tid, kt2);
        stage(B, K_, nT, buf, 4096, tid, kt2);
    };
    auto stage_ph1 = [&](int t) {
        int buf = t % 3, kt2 = t * 32;
        stage(B, K_, nT, buf, 4096, 256 + tid, kt2);
        stage(B, K_, nT, buf, 4096, 512 + tid, kt2);
        stage(B, K_, nT, buf, 4096, 768 + tid, kt2);
    };

    f32x4 acc[8][4] = {};
    bf16x8 bfr[4];
    const int swd = ((l >> 4) ^ (l15 >> 1)) & 3;   // swizzled read slot

    // prologue: fully stage tiles 0 and 1
    stage_ph0(0); stage_ph1(0);
    stage_ph0(1); stage_ph1(1);

    for (int t = 0; t < NT; ++t) {
        // tile entry: per-wave counted wait, then workgroup barrier
        if (t + 1 < NT) asm volatile("s_waitcnt vmcnt(6)" ::: "memory");
        else            asm volatile("s_waitcnt vmcnt(0)" ::: "memory");
        __builtin_amdgcn_s_barrier();

        const ushort* Ab = smem + (t % 3) * 12288;
        const ushort* Bb = Ab + 4096;
        const bool st = (t + 2 < NT);

        // ---- phase 0: frags (B all + A mi 0-3), stage half, 16 MFMA ----
        bf16x8 af[4];
        #pragma unroll
        for (int i = 0; i < 4; ++i)
            af[i] = *reinterpret_cast<const bf16x8*>(
                &Ab[(i * 16 + l15) * 32 + swd * 8]);
        #pragma unroll
        for (int j = 0; j < 4; ++j)
            bfr[j] = *reinterpret_cast<const bf16x8*>(
                &Bb[(w * 64 + j * 16 + l15) * 32 + swd * 8]);
        if (st) stage_ph0(t + 2);
        asm volatile("s_waitcnt lgkmcnt(0)" ::: "memory");
        __builtin_amdgcn_sched_barrier(0);
        __builtin_amdgcn_s_setprio(1);
        #pragma unroll
        for (int i = 0; i < 4; ++i)
            #pragma unroll
            for (int j = 0; j < 4; ++j)
                acc[i][j] = __builtin_amdgcn_mfma_f32_16x16x32_bf16(
                    af[i], bfr[j], acc[i][j], 0, 0, 0);
        __builtin_amdgcn_s_setprio(0);
        __builtin_amdgcn_s_barrier();

        // ---- phase 1: frags (A mi 4-7), stage half, 16 MFMA ----
        #pragma unroll
        for (int i = 0; i < 4; ++i)
            af[i] = *reinterpret_cast<const bf16x8*>(
                &Ab[((4 + i) * 16 + l15) * 32 + swd * 8]);
        if (st) stage_ph1(t + 2);
        asm volatile("s_waitcnt lgkmcnt(0)" ::: "memory");
        __builtin_amdgcn_sched_barrier(0);
        __builtin_amdgcn_s_setprio(1);
        #pragma unroll
        for (int i = 0; i < 4; ++i)
            #pragma unroll
            for (int j = 0; j < 4; ++j)
                acc[4 + i][j] = __builtin_amdgcn_mfma_f32_16x16x32_bf16(
                    af[i], bfr[j], acc[4 + i][j], 0, 0, 0);
        __builtin_amdgcn_s_setprio(0);
        __builtin_amdgcn_s_barrier();
    }

    // epilogue: C/D layout col=lane&15, row=(lane>>4)*4+q
    const int row0 = (l >> 4) * 4;
    #pragma unroll
    for (int ni = 0; ni < 4; ++ni) {
        int col = nT + w * 64 + ni * 16 + l15;
        float bv = bias ? bias[col] : 0.f;
        #pragma unroll
        for (int mi = 0; mi < 8; ++mi) {
            #pragma unroll
            for (int q = 0; q < 4; ++q) {
                int row = mT + mi * 16 + row0 + q;
                float val = acc[mi][ni][q] + bv;
                if constexpr (sizeof(CT) == 2)
                    C[(size_t)row * N_ + col] = (CT)f2bf(val);
                else
                    C[(size_t)row * N_ + col] = (CT)val;
            }
        }
    }
}

template<typename CT>
void launch_gemm(const ushort* A, int lda, const ushort* B, CT* C,
                 const float* bias, int M_, int N_, int K_, hipStream_t stream)
{
    dim3 grid(N_ / 256, M_ / 128);
    gemm_bf16<CT><<<grid, 256, 0, stream>>>(A, B, C, bias, M_, N_, K_, lda);
}

// ---- Av[b,v,e] = sum_u adj[b,u,v]*Hu[b,u,e] + deg[b,v]*St[b,v,e] -----------
// HuSt bf16 (M,2048): Hu = cols 0-1023, St = cols 1024-2047. Out: AvH bf16.
__global__ __launch_bounds__(256) void av_kernel(const float* __restrict__ adj,
    const ushort* __restrict__ HuSt, const float* __restrict__ deg,
    ushort* __restrict__ AvH)
{
    __shared__ float adjs[kN * kN];
    __shared__ float degs[kN];
    int b = blockIdx.y;
    int e = blockIdx.x * 256 + threadIdx.x;  // < 1024
    {
        const float4* src = reinterpret_cast<const float4*>(adj + (size_t)b * kN * kN);
        float4 v = src[threadIdx.x];
        *reinterpret_cast<float4*>(&adjs[threadIdx.x * 4]) = v;
        if (threadIdx.x < kN) degs[threadIdx.x] = deg[b * kN + threadIdx.x];
    }
    __syncthreads();

    const size_t rbase = (size_t)b * kN * 2048 + e;
    float acc[kN];
    #pragma unroll
    for (int v = 0; v < kN; ++v)
        acc[v] = degs[v] * bf2f(HuSt[rbase + (size_t)v * 2048 + kHS2]);
    for (int u = 0; u < kN; ++u) {
        float hu = bf2f(HuSt[rbase + (size_t)u * 2048]);
        #pragma unroll
        for (int v4 = 0; v4 < kN / 4; ++v4) {
            float4 a = *reinterpret_cast<const float4*>(&adjs[u * kN + v4 * 4]);
            acc[v4 * 4 + 0] = fmaf(a.x, hu, acc[v4 * 4 + 0]);
            acc[v4 * 4 + 1] = fmaf(a.y, hu, acc[v4 * 4 + 1]);
            acc[v4 * 4 + 2] = fmaf(a.z, hu, acc[v4 * 4 + 2]);
            acc[v4 * 4 + 3] = fmaf(a.w, hu, acc[v4 * 4 + 3]);
        }
    }
    const size_t obase = (size_t)b * kN * kHS3 + e;
    #pragma unroll
    for (int v = 0; v < kN; ++v) AvH[obase + (size_t)v * kHS3] = f2bf(acc[v]);
}

// ---------------- GRU gating + has_pred select (H bf16 inside AvH) ----------
// gxzn bf16 (M,1536): r=cols[0,512), z=[512,1024), xn=[1024,1536). hn bf16 (M,512).
__global__ __launch_bounds__(256) void gru_kernel(ushort* __restrict__ AvH,
    const ushort* __restrict__ gxzn, const ushort* __restrict__ hn,
    const int* __restrict__ hp)
{
    int idx = blockIdx.x * 256 + threadIdx.x;  // < MC*kHS
    int m = idx >> 9;
    int h = idx & 511;
    size_t gb = (size_t)m * kHS3 + h;
    float rp = bf2f(gxzn[gb]);
    float zp = bf2f(gxzn[gb + kHS]);
    float xn = bf2f(gxzn[gb + 2 * kHS]);
    float hv = bf2f(hn[(size_t)m * kHS + h]);
    float r = 1.f / (1.f + __expf(-rp));
    float z = 1.f / (1.f + __expf(-zp));
    float n = tanhf(xn + r * hv);
    ushort* Hp = AvH + (size_t)m * kHS3 + kHS2 + h;
    float hold = bf2f(*Hp);
    float hnew = (1.f - z) * n + z * hold;
    *Hp = hp[m & 31] ? f2bf(hnew) : f2bf(hold);
}

// ---------------- Hg[b,g] = sum_n sigmoid(G1) * G2 --------------------------
// G12 f32 (M,2048): G1 = cols 0-1023 (incl gate_b), G2 = cols 1024-2047
__global__ __launch_bounds__(256) void hg_kernel(const float* __restrict__ G12,
    float* __restrict__ Hg)
{
    int idx = blockIdx.x * 256 + threadIdx.x;  // < CH*kGS
    int b = idx >> 10, g = idx & 1023;
    size_t base = (size_t)b * kN * 2048 + g;
    float acc = 0.f;
    #pragma unroll 8
    for (int n = 0; n < kN; ++n) {
        float s  = G12[base + (size_t)n * 2048];
        float m2 = G12[base + (size_t)n * 2048 + kGS];
        float sig = 1.f / (1.f + __expf(-s));
        acc = fmaf(sig, m2, acc);
    }
    Hg[idx] = acc;
}

// ---------------- mu/logvar heads -------------------------------------------
__global__ __launch_bounds__(64) void fc_kernel(const float* __restrict__ Hg,
    const float* __restrict__ fc1_w, const float* __restrict__ fc1_b,
    const float* __restrict__ fc2_w, const float* __restrict__ fc2_b,
    float* __restrict__ out, int b0)
{
    __shared__ float hg[kGS];
    int bl = blockIdx.x;
    for (int i = threadIdx.x; i < kGS; i += 64) hg[i] = Hg[(size_t)bl * kGS + i];
    __syncthreads();
    int j = threadIdx.x;
    if (j < kNZ) {
        float s1 = fc1_b[j], s2 = fc2_b[j];
        for (int k = 0; k < kGS; ++k) {
            float h = hg[k];
            s1 = fmaf(h, fc1_w[k * kNZ + j], s1);
            s2 = fmaf(h, fc2_w[k * kNZ + j], s2);
        }
        int bg = b0 + bl;
        out[(size_t)bg * kNZ + j] = s1;
        out[(size_t)kB * kNZ + (size_t)bg * kNZ + j] = s2;
    }
}

}  // namespace

extern "C" void kernel_launch(void* const* d_in, const int* in_sizes, int n_in,
                              void* d_out, int out_size, void* d_ws, size_t ws_size,
                              hipStream_t stream)
{
    const int*   node_types = (const int*)  d_in[0];
    const float* adj        = (const float*)d_in[1];
    const float* finit_w    = (const float*)d_in[2];
    const float* finit_b    = (const float*)d_in[3];
    const float* fe_w       = (const float*)d_in[4];
    const float* fe_b       = (const float*)d_in[5];
    const float* grue_wih   = (const float*)d_in[6];
    const float* grue_whh   = (const float*)d_in[7];
    const float* grue_bih   = (const float*)d_in[8];
    const float* grue_bhh   = (const float*)d_in[9];
    const float* gate_w     = (const float*)d_in[10];
    const float* gate_b     = (const float*)d_in[11];
    const float* mapper_w   = (const float*)d_in[12];
    const float* fc1_w      = (const float*)d_in[13];
    const float* fc1_b      = (const float*)d_in[14];
    const float* fc2_w      = (const float*)d_in[15];
    const float* fc2_b      = (const float*)d_in[16];
    float* out = (float*)d_out;

    // ---- fixed region (float units) ----
    float* W = (float*)d_ws;
    size_t o = 0;
    float*  deg     = W + o; o += (size_t)kB * kN;
    int*    hp      = (int*)(W + o); o += 64;
    float*  biasHS  = W + o; o += 2048;
    float*  biasGXN = W + o; o += kTE * kHS3;
    float*  biasRO  = W + o; o += 2048;
    float*  Hg      = W + o; o += (size_t)kB * kGS;
    ushort* WnsT    = (ushort*)(W + o); o += (size_t)2048 * kHS / 2;
    ushort* catRZN  = (ushort*)(W + o); o += (size_t)kTE * kHS3 * kHS3 / 2;
    ushort* whhN    = (ushort*)(W + o); o += (size_t)kTE * kHS * kHS / 2;
    ushort* gateMapT= (ushort*)(W + o); o += (size_t)2048 * kHS / 2;
    const size_t fixedFloats = o;

    // per-graph floats: AvH 24576 + HuSt 32768 + gxzn 24576 + hn 8192 = 90112
    const size_t perGraph = 90112;
    int CH = 512;
    while (CH > 4 &&
           (fixedFloats + (size_t)CH * perGraph) * sizeof(float) > ws_size)
        CH >>= 1;

    // ---- one-time precompute ----
    deg_kernel<<<kB * kN / 256, 256, 0, stream>>>(adj, deg);
    haspred_kernel<<<1, kN, 0, stream>>>(deg, hp);
    biasHS_kernel<<<2048 / 256, 256, 0, stream>>>(fe_w, fe_b, biasHS);
    biasGXN_kernel<<<kTE * kHS3 / 256, 256, 0, stream>>>(grue_bih, grue_bhh, biasGXN);
    biasRO_kernel<<<2048 / 256, 256, 0, stream>>>(gate_b, biasRO);
    wnst_kernel<<<2048 * kHS / 256, 256, 0, stream>>>(fe_w, WnsT);
    catrzn_kernel<<<dim3(kHS3 / 256, kHS3, kTE), 256, 0, stream>>>(grue_wih, grue_whh, catRZN);
    whhn_kernel<<<dim3(kHS / 256, kHS, kTE), 256, 0, stream>>>(grue_whh, whhN);
    gatemap_kernel<<<2048 * kHS / 256, 256, 0, stream>>>(gate_w, mapper_w, gateMapT);

    for (int b0 = 0; b0 < kB; b0 += CH) {
        const int MC = CH * kN;  // rows (multiple of 128)
        ushort* AvH  = (ushort*)(W + fixedFloats);        // MC x 1536 bf16
        ushort* HuSt = AvH  + (size_t)MC * kHS3;          // MC x 2048 bf16
        ushort* gxzn = HuSt + (size_t)MC * 2048;          // MC x 1536 bf16
        ushort* hnb  = gxzn + (size_t)MC * kHS3;          // MC x 512  bf16
        float*  G12  = (float*)HuSt;                      // MC x 2048 f32 (overlay)
        ushort* Hc   = AvH + kHS2;                        // H view, lda 1536

        hinit_kernel<<<MC * kHS / 256, 256, 0, stream>>>(
            node_types + (size_t)b0 * kN, finit_w, finit_b, AvH);

        for (int t = 0; t < kTE; ++t) {
            // HuSt = H @ WnsT^T + [0 | we+fe_b]   (MC x 2048, bf16)
            launch_gemm<ushort>(Hc, kHS3, WnsT, HuSt, biasHS, MC, 2048, kHS, stream);
            // Av -> AvH[:, 0:1024]
            {
                dim3 g(kHS2 / 256, CH);
                av_kernel<<<g, 256, 0, stream>>>(
                    adj + (size_t)b0 * kN * kN, HuSt, deg + (size_t)b0 * kN, AvH);
            }
            // gxzn = [Av|H] @ catRZN[t]^T + biasGXN[t]   (MC x 1536, K=1536)
            launch_gemm<ushort>(AvH, kHS3, catRZN + (size_t)t * kHS3 * kHS3, gxzn,
                                biasGXN + t * kHS3, MC, kHS3, kHS3, stream);
            // hn = H @ whhN[t]^T + bhh_n   (MC x 512)
            launch_gemm<ushort>(Hc, kHS3, whhN + (size_t)t * kHS * kHS, hnb,
                                grue_bhh + t * kHS3 + kHS2, MC, kHS, kHS, stream);
            // GRU gating (H in place)
            gru_kernel<<<MC * kHS / 256, 256, 0, stream>>>(AvH, gxzn, hnb, hp);
        }

        // readout: G12 = H @ [gate|mapper]^T + [gate_b|0]  (MC x 2048, f32)
        launch_gemm<float>(Hc, kHS3, gateMapT, G12, biasRO, MC, 2048, kHS, stream);
        hg_kernel<<<CH * kGS / 256, 256, 0, stream>>>(G12, Hg);
        fc_kernel<<<CH, 64, 0, stream>>>(Hg, fc1_w, fc1_b, fc2_w, fc2_b, out, b0);
    }
}